// Round 2
// baseline (144.649 us; speedup 1.0000x reference)
//
#include <hip/hip_runtime.h>
#include <hip/hip_bf16.h>
#include <stdint.h>

// TypedLinear: out[i] = W[types[i]] @ x[i] + b[types[i]]
// N=65536, IN=OUT=256, T=8, fp32 in/out. bf16-MFMA grouped-GEMM.
// R2: atomic-free bucketing + exact tile worklist + double-buffered pipelined GEMM.

#define NROWS 65536
#define NTYPES 8
#define KDIM 256
#define ODIM 256
#define BM 128
#define BN 128
#define BK 64
#define HB 64          // histogram blocks (x1024 threads)
#define MAXTILES 544   // >= worst-case sum ceil(cnt[t]/128) = 519

typedef __attribute__((ext_vector_type(8))) short short8;
typedef __attribute__((ext_vector_type(4))) float f32x4;

__device__ __forceinline__ unsigned short f2bf(float f) {
    unsigned int u = __float_as_uint(f);
    u += 0x7fffu + ((u >> 16) & 1u);   // RNE
    return (unsigned short)(u >> 16);
}

// ---- phase 1: per-block type histogram + W fp32->bf16 (fused) ----
__global__ void prep_hist_kernel(const int* __restrict__ types,
                                 const float* __restrict__ W,
                                 unsigned short* __restrict__ Wb,
                                 int* __restrict__ blockHist) {
    __shared__ int h[NTYPES];
    const int tid = threadIdx.x;
    if (tid < NTYPES) h[tid] = 0;
    __syncthreads();
    const int i = blockIdx.x * 1024 + tid;
    atomicAdd(&h[types[i]], 1);
    // W: 131072 float4 over 65536 threads -> 2 each
    #pragma unroll
    for (int r = 0; r < 2; ++r) {
        int j = i + r * 65536;
        float4 v = ((const float4*)W)[j];
        ushort4 p;
        p.x = f2bf(v.x); p.y = f2bf(v.y); p.z = f2bf(v.z); p.w = f2bf(v.w);
        ((ushort4*)Wb)[j] = p;
    }
    __syncthreads();
    if (tid < NTYPES) blockHist[blockIdx.x * NTYPES + tid] = h[tid];
}

// ---- phase 2: scan (1 block, 64 thr): bases + compact offsets + tile list ----
__global__ void scan_kernel(const int* __restrict__ blockHist,
                            int* __restrict__ blockBase,
                            int* __restrict__ typeBase,
                            int4* __restrict__ tiles,
                            int* __restrict__ tileCount) {
    __shared__ int scnt[NTYPES], sTypeBase[NTYPES], sTileBase[NTYPES + 1];
    const int tid = threadIdx.x;
    if (tid < NTYPES) {
        int run = 0;
        for (int b = 0; b < HB; ++b) {
            blockBase[b * NTYPES + tid] = run;
            run += blockHist[b * NTYPES + tid];
        }
        scnt[tid] = run;
    }
    __syncthreads();
    if (tid == 0) {
        int rowacc = 0, tileacc = 0;
        for (int t = 0; t < NTYPES; ++t) {
            sTypeBase[t] = rowacc; typeBase[t] = rowacc; rowacc += scnt[t];
            sTileBase[t] = tileacc; tileacc += (scnt[t] + BM - 1) / BM;
        }
        sTileBase[NTYPES] = tileacc;
        tileCount[0] = tileacc;
    }
    __syncthreads();
    const int tc = sTileBase[NTYPES];
    for (int j = tid; j < MAXTILES; j += 64) {
        if (j < tc) {
            int t = 0;
            while (t < NTYPES - 1 && j >= sTileBase[t + 1]) ++t;
            tiles[j] = make_int4(t, (j - sTileBase[t]) * BM, sTypeBase[t], scnt[t]);
        }
    }
}

// ---- phase 3: scatter rows into compact per-type index lists (no global atomics) ----
__global__ void scatter_kernel(const int* __restrict__ types,
                               const int* __restrict__ blockBase,
                               const int* __restrict__ typeBase,
                               int* __restrict__ idx) {
    __shared__ int h[NTYPES];
    __shared__ int base[NTYPES];
    const int tid = threadIdx.x;
    if (tid < NTYPES) {
        h[tid] = 0;
        base[tid] = typeBase[tid] + blockBase[blockIdx.x * NTYPES + tid];
    }
    __syncthreads();
    const int i = blockIdx.x * 1024 + tid;
    const int t = types[i];
    int r = atomicAdd(&h[t], 1);   // LDS only
    idx[base[t] + r] = i;
}

// ---- phase 4: grouped GEMM, tile-list driven, double-buffered pipeline ----
// 256 thr = 4 waves (2x2 of 64x64), mfma_f32_16x16x32_bf16, 16B-chunk XOR swizzle.
// LDS = exactly 64 KB (2 buffers of A 16KB + B 16KB) -> 2 blocks/CU.
__global__ __launch_bounds__(256, 2)
void gemm_kernel(const float* __restrict__ x,
                 const float* __restrict__ bias,
                 const unsigned short* __restrict__ Wb,
                 const int* __restrict__ tileCount,
                 const int4* __restrict__ tiles,
                 const int* __restrict__ idx,
                 float* __restrict__ out) {
    if ((int)blockIdx.x >= tileCount[0]) return;   // uniform, pre-barrier
    const int4 td = tiles[blockIdx.x];
    const int t = td.x, m0 = td.y, rbase = td.z, count = td.w;
    const int n0 = blockIdx.y * BN;
    const int rem = count - m0;                    // >= 1 by construction

    __shared__ unsigned short As[2][BM * BK];      // 2 x 16 KB, swizzled
    __shared__ unsigned short Bs[2][BN * BK];      // 2 x 16 KB, swizzled

    const int tid = threadIdx.x;
    const int wave = tid >> 6;
    const int lane = tid & 63;
    const int lr = lane & 15;
    const int lq = lane >> 4;
    const int wm = (wave >> 1) * 64;
    const int wn = (wave & 1) * 64;

    const int* rowIdx = idx + rbase + m0;

    // A staging: 16 threads/row (float4 each), 8 rows/thread
    const int srow = tid >> 4;
    const int sc = tid & 15;
    const float* aptr[8];
    #pragma unroll
    for (int j = 0; j < 8; ++j) {
        int m = j * 16 + srow;
        aptr[j] = x + (size_t)rowIdx[m < rem ? m : 0] * KDIM + sc * 4;
    }

    // bias into registers (kills the LDS bias tile)
    float breg[4];
    #pragma unroll
    for (int j = 0; j < 4; ++j) breg[j] = bias[t * ODIM + n0 + wn + j * 16 + lr];

    // B staging via global_load_lds: swizzle applied on SOURCE address
    const int bschunk = (lane & 7) ^ (lane >> 3);
    const unsigned short* bsrc0 = Wb + (size_t)t * ODIM * KDIM + (size_t)bschunk * 8;

    f32x4 acc[4][4] = {};
    float4 av[8];

#define ISSUE_B(buf, k0)                                                        \
    {                                                                           \
        _Pragma("unroll")                                                       \
        for (int it = 0; it < 4; ++it) {                                        \
            int dbyte = wave * 4096 + it * 1024;                                \
            int row = (dbyte >> 7) + (lane >> 3);                               \
            const unsigned short* src = bsrc0 + (size_t)(n0 + row) * KDIM + (k0); \
            __builtin_amdgcn_global_load_lds(                                   \
                (const __attribute__((address_space(1))) void*)src,             \
                (__attribute__((address_space(3))) void*)((char*)Bs[buf] + dbyte), \
                16, 0, 0);                                                      \
        }                                                                       \
    }

#define LOAD_A(k0)                                                              \
    {                                                                           \
        _Pragma("unroll")                                                       \
        for (int j = 0; j < 8; ++j) av[j] = *(const float4*)(aptr[j] + (k0));   \
    }

#define WRITE_A(buf)                                                            \
    {                                                                           \
        _Pragma("unroll")                                                       \
        for (int j = 0; j < 8; ++j) {                                           \
            int row = j * 16 + srow;                                            \
            ushort4 p;                                                          \
            p.x = f2bf(av[j].x); p.y = f2bf(av[j].y);                           \
            p.z = f2bf(av[j].z); p.w = f2bf(av[j].w);                           \
            int ch = (sc >> 1) ^ (row & 7);                                     \
            *(ushort4*)((char*)As[buf] + row * 128 + ch * 16 + (sc & 1) * 8) = p; \
        }                                                                       \
    }

    // prologue: fill buffer 0
    ISSUE_B(0, 0);
    LOAD_A(0);
    WRITE_A(0);
    __syncthreads();   // publishes As[0]; vmcnt drain completes Bs[0]

    #pragma unroll
    for (int i = 0; i < 4; ++i) {
        const int cur = i & 1;
        if (i < 3) {
            ISSUE_B(cur ^ 1, (i + 1) * BK);   // in flight during compute
            LOAD_A((i + 1) * BK);
        }
        // compute on buffer `cur`
        #pragma unroll
        for (int kh = 0; kh < 2; ++kh) {
            short8 af[4], bfr[4];
            #pragma unroll
            for (int q = 0; q < 4; ++q) {
                int arow = wm + q * 16 + lr;
                int ach = ((kh << 2) + lq) ^ (arow & 7);
                af[q] = *(const short8*)((char*)As[cur] + arow * 128 + ach * 16);
            }
            #pragma unroll
            for (int q = 0; q < 4; ++q) {
                int brow = wn + q * 16 + lr;
                int bch = ((kh << 2) + lq) ^ (brow & 7);
                bfr[q] = *(const short8*)((char*)Bs[cur] + brow * 128 + bch * 16);
            }
            #pragma unroll
            for (int q = 0; q < 4; ++q)
                #pragma unroll
                for (int j = 0; j < 4; ++j)
                    acc[q][j] = __builtin_amdgcn_mfma_f32_16x16x32_bf16(
                        af[q], bfr[j], acc[q][j], 0, 0, 0);
        }
        if (i < 3) {
            WRITE_A(cur ^ 1);
            __syncthreads();   // publish next buffers (B glds drained here too)
        }
    }

    // epilogue: D col = lane&15, row = (lane>>4)*4 + reg
    #pragma unroll
    for (int q = 0; q < 4; ++q) {
        #pragma unroll
        for (int r = 0; r < 4; ++r) {
            int lm = wm + q * 16 + lq * 4 + r;
            if (lm < rem) {
                size_t orow = (size_t)rowIdx[lm] * ODIM + n0;
                #pragma unroll
                for (int j = 0; j < 4; ++j)
                    out[orow + wn + j * 16 + lr] = acc[q][j][r] + breg[j];
            }
        }
    }
#undef ISSUE_B
#undef LOAD_A
#undef WRITE_A
}

extern "C" void kernel_launch(void* const* d_in, const int* in_sizes, int n_in,
                              void* d_out, int out_size, void* d_ws, size_t ws_size,
                              hipStream_t stream) {
    const float* x     = (const float*)d_in[0];
    const int*   types = (const int*)d_in[1];
    const float* W     = (const float*)d_in[2];
    const float* b     = (const float*)d_in[3];
    float* out = (float*)d_out;

    // ws layout (bytes):
    //     0: tileCount (int)
    //   128: typeBase[8]
    //   512: blockHist[64][8]   (2 KB)
    //  2560: blockBase[64][8]   (2 KB)
    //  4608: tiles[544] int4    (8.5 KB)
    // 16384: idx[65536]         (256 KB)
    // 278528: Wb bf16[8*256*256] (1 MB)
    char* ws = (char*)d_ws;
    int*  tileCount = (int*)ws;
    int*  typeBase  = (int*)(ws + 128);
    int*  blockHist = (int*)(ws + 512);
    int*  blockBase = (int*)(ws + 2560);
    int4* tiles     = (int4*)(ws + 4608);
    int*  idx       = (int*)(ws + 16384);
    unsigned short* Wb = (unsigned short*)(ws + 278528);

    prep_hist_kernel<<<HB, 1024, 0, stream>>>(types, W, Wb, blockHist);
    scan_kernel<<<1, 64, 0, stream>>>(blockHist, blockBase, typeBase, tiles, tileCount);
    scatter_kernel<<<HB, 1024, 0, stream>>>(types, blockBase, typeBase, idx);
    gemm_kernel<<<dim3(MAXTILES, 2), 256, 0, stream>>>(x, b, Wb, tileCount, tiles, idx, out);
}

// Round 3
// 143.897 us; speedup vs baseline: 1.0052x; 1.0052x over previous
//
#include <hip/hip_runtime.h>
#include <hip/hip_bf16.h>
#include <stdint.h>

// TypedLinear: out[i] = W[types[i]] @ x[i] + b[types[i]]
// N=65536, IN=OUT=256, T=8, fp32 in/out. bf16-MFMA grouped-GEMM.
// R3: BN=256 (x read once), 512-thr blocks, 16 waves/CU occupancy cap,
//     fully-parallel LDS-resident bucketing (no serial scan, no global atomics).

#define NROWS 65536
#define NTYPES 8
#define KDIM 256
#define ODIM 256
#define BM 128
#define BN 256
#define BK 64
#define HB 256         // histogram blocks (x256 threads)
#define MAXTILES 640   // >= worst-case sum ceil(cnt[t]/128) ~ 520

typedef __attribute__((ext_vector_type(8))) short short8;
typedef __attribute__((ext_vector_type(4))) float f32x4;

__device__ __forceinline__ unsigned short f2bf(float f) {
    unsigned int u = __float_as_uint(f);
    u += 0x7fffu + ((u >> 16) & 1u);   // RNE
    return (unsigned short)(u >> 16);
}

// ---- K1: per-block type histogram + W fp32->bf16 (fused) ----
__global__ void hist_kernel(const int* __restrict__ types,
                            const float* __restrict__ W,
                            unsigned short* __restrict__ Wb,
                            int* __restrict__ blockHist) {
    __shared__ int h[NTYPES];
    const int tid = threadIdx.x;
    if (tid < NTYPES) h[tid] = 0;
    __syncthreads();
    const int i = blockIdx.x * 256 + tid;
    atomicAdd(&h[types[i]], 1);   // LDS only
    // W: 131072 float4 over 256 blocks x 256 thr -> 2 each
    #pragma unroll
    for (int r = 0; r < 2; ++r) {
        int j = blockIdx.x * 512 + r * 256 + tid;
        float4 v = ((const float4*)W)[j];
        ushort4 p;
        p.x = f2bf(v.x); p.y = f2bf(v.y); p.z = f2bf(v.z); p.w = f2bf(v.w);
        ((ushort4*)Wb)[j] = p;
    }
    __syncthreads();
    if (tid < NTYPES) blockHist[blockIdx.x * NTYPES + tid] = h[tid];
}

// ---- K2: scan + tile list, 1 block x 256 thr, all LDS-resident ----
// 8 types x 256 block-counts. Type t owned by 32-lane segment; each lane owns
// 8 consecutive blocks; segmented shuffle scan across the 32 lanes.
__global__ void scan_kernel(const int* __restrict__ blockHist,
                            int* __restrict__ blockBase,
                            int* __restrict__ typeBase,
                            int4* __restrict__ tiles,
                            int* __restrict__ tileCount) {
    __shared__ int v[HB * NTYPES];          // 8 KB
    __shared__ int scnt[NTYPES];
    __shared__ int sTypeBase[NTYPES], sTileBase[NTYPES + 1];
    const int tid = threadIdx.x;
    for (int j = tid; j < HB * NTYPES; j += 256) v[j] = blockHist[j];
    __syncthreads();

    const int t = tid >> 5;          // 0..7
    const int l = tid & 31;          // lane in segment
    int s[8];
    int sum = 0;
    #pragma unroll
    for (int m = 0; m < 8; ++m) {
        s[m] = sum;                  // exclusive within this lane's chunk
        sum += v[(l * 8 + m) * NTYPES + t];
    }
    // segmented (width=32) inclusive scan of `sum`
    int incl = sum;
    #pragma unroll
    for (int d = 1; d < 32; d <<= 1) {
        int y = __shfl_up(incl, d, 32);
        if (l >= d) incl += y;
    }
    const int excl = incl - sum;
    #pragma unroll
    for (int m = 0; m < 8; ++m)
        blockBase[(l * 8 + m) * NTYPES + t] = excl + s[m];
    if (l == 31) scnt[t] = incl;     // type total
    __syncthreads();

    if (tid == 0) {
        int rowacc = 0, tileacc = 0;
        for (int q = 0; q < NTYPES; ++q) {
            sTypeBase[q] = rowacc; typeBase[q] = rowacc; rowacc += scnt[q];
            sTileBase[q] = tileacc; tileacc += (scnt[q] + BM - 1) / BM;
        }
        sTileBase[NTYPES] = tileacc;
        tileCount[0] = tileacc;
    }
    __syncthreads();
    const int tc = sTileBase[NTYPES];
    for (int j = tid; j < tc; j += 256) {
        int q = 0;
        while (q < NTYPES - 1 && j >= sTileBase[q + 1]) ++q;
        tiles[j] = make_int4(q, (j - sTileBase[q]) * BM, sTypeBase[q], scnt[q]);
    }
}

// ---- K3: scatter rows into compact per-type lists (LDS atomics only) ----
__global__ void scatter_kernel(const int* __restrict__ types,
                               const int* __restrict__ blockBase,
                               const int* __restrict__ typeBase,
                               int* __restrict__ idx) {
    __shared__ int h[NTYPES];
    __shared__ int base[NTYPES];
    const int tid = threadIdx.x;
    if (tid < NTYPES) {
        h[tid] = 0;
        base[tid] = typeBase[tid] + blockBase[blockIdx.x * NTYPES + tid];
    }
    __syncthreads();
    const int i = blockIdx.x * 256 + tid;
    const int t = types[i];
    int r = atomicAdd(&h[t], 1);
    idx[base[t] + r] = i;
}

// ---- K4: grouped GEMM. 512 thr = 8 waves (2M x 4N of 64x64), BN=256,
//      single-buffered 48 KB LDS, 16B-chunk XOR swizzle.
__global__ __launch_bounds__(512, 4)
void gemm_kernel(const float* __restrict__ x,
                 const float* __restrict__ bias,
                 const unsigned short* __restrict__ Wb,
                 const int* __restrict__ tileCount,
                 const int4* __restrict__ tiles,
                 const int* __restrict__ idx,
                 float* __restrict__ out) {
    if ((int)blockIdx.x >= tileCount[0]) return;   // uniform, pre-barrier
    const int4 td = tiles[blockIdx.x];
    const int t = td.x, m0 = td.y, rbase = td.z, count = td.w;
    const int rem = count - m0;                    // >= 1

    __shared__ unsigned short As[BM * BK];         // 16 KB
    __shared__ unsigned short Bs[BN * BK];         // 32 KB

    const int tid = threadIdx.x;
    const int wave = tid >> 6;
    const int lane = tid & 63;
    const int lr = lane & 15;
    const int lq = lane >> 4;
    const int wm = (wave & 1) * 64;        // M offset
    const int wn = (wave >> 1) * 64;       // N offset (4 waves cover 256)

    const int* rowIdx = idx + rbase + m0;

    // A staging: 16 thr/row (one float4 each), 32 rows/pass, 4 passes
    const int srow = tid >> 4;             // 0..31
    const int sc = tid & 15;
    const float* aptr[4];
    #pragma unroll
    for (int j = 0; j < 4; ++j) {
        int m = j * 32 + srow;
        aptr[j] = x + (size_t)rowIdx[m < rem ? m : 0] * KDIM + sc * 4;
    }

    float breg[4];
    #pragma unroll
    for (int j = 0; j < 4; ++j) breg[j] = bias[t * ODIM + wn + j * 16 + lr];

    // B staging via global_load_lds (swizzle folded into SOURCE address)
    const int bschunk = (lane & 7) ^ (lane >> 3);
    const unsigned short* bsrc0 = Wb + (size_t)t * ODIM * KDIM + (size_t)bschunk * 8;

    f32x4 acc[4][4] = {};
    char* AsB = (char*)As;
    char* BsB = (char*)Bs;

    for (int k0 = 0; k0 < KDIM; k0 += BK) {
        // B: 4 issues x 512 lanes x 16B = 32 KB
        #pragma unroll
        for (int it = 0; it < 4; ++it) {
            int dbyte = it * 8192 + wave * 1024;   // wave-uniform base
            int row = (dbyte >> 7) + (lane >> 3);  // row&7 == lane>>3
            const unsigned short* src = bsrc0 + (size_t)row * KDIM + k0;
            __builtin_amdgcn_global_load_lds(
                (const __attribute__((address_space(1))) void*)src,
                (__attribute__((address_space(3))) void*)(BsB + dbyte),
                16, 0, 0);
        }
        // A: gather 128 rows x 64 fp32 -> bf16, swizzled
        #pragma unroll
        for (int j = 0; j < 4; ++j) {
            int row = j * 32 + srow;
            const float4 v = *(const float4*)(aptr[j] + k0);
            ushort4 p;
            p.x = f2bf(v.x); p.y = f2bf(v.y); p.z = f2bf(v.z); p.w = f2bf(v.w);
            int ch = (sc >> 1) ^ (row & 7);
            *(ushort4*)(AsB + row * 128 + ch * 16 + (sc & 1) * 8) = p;
        }
        __syncthreads();   // publishes As + drains B glds

        #pragma unroll
        for (int kh = 0; kh < 2; ++kh) {
            short8 af[4], bfr[4];
            #pragma unroll
            for (int q = 0; q < 4; ++q) {
                int arow = wm + q * 16 + lr;
                int ach = ((kh << 2) + lq) ^ (arow & 7);
                af[q] = *(const short8*)(AsB + arow * 128 + ach * 16);
            }
            #pragma unroll
            for (int q = 0; q < 4; ++q) {
                int brow = wn + q * 16 + lr;
                int bch = ((kh << 2) + lq) ^ (brow & 7);
                bfr[q] = *(const short8*)(BsB + brow * 128 + bch * 16);
            }
            #pragma unroll
            for (int q = 0; q < 4; ++q)
                #pragma unroll
                for (int j = 0; j < 4; ++j)
                    acc[q][j] = __builtin_amdgcn_mfma_f32_16x16x32_bf16(
                        af[q], bfr[j], acc[q][j], 0, 0, 0);
        }
        __syncthreads();   // LDS free for next iteration's staging
    }

    // epilogue: D col = lane&15, row = (lane>>4)*4 + reg
    #pragma unroll
    for (int q = 0; q < 4; ++q) {
        #pragma unroll
        for (int r = 0; r < 4; ++r) {
            int lm = wm + q * 16 + lq * 4 + r;
            if (lm < rem) {
                size_t orow = (size_t)rowIdx[lm] * ODIM;
                #pragma unroll
                for (int j = 0; j < 4; ++j)
                    out[orow + wn + j * 16 + lr] = acc[q][j][r] + breg[j];
            }
        }
    }
}

extern "C" void kernel_launch(void* const* d_in, const int* in_sizes, int n_in,
                              void* d_out, int out_size, void* d_ws, size_t ws_size,
                              hipStream_t stream) {
    const float* x     = (const float*)d_in[0];
    const int*   types = (const int*)d_in[1];
    const float* W     = (const float*)d_in[2];
    const float* b     = (const float*)d_in[3];
    float* out = (float*)d_out;

    // ws layout (bytes):
    //      0: tileCount
    //    128: typeBase[8]
    //    512: blockHist[256*8]  (8 KB)
    //   9216: blockBase[256*8]  (8 KB)
    //  17408: tiles[640] int4   (10 KB)
    //  32768: idx[65536]        (256 KB)
    // 294912: Wb bf16[8*256*256] (1 MB)   -> total ~1.3 MB
    char* ws = (char*)d_ws;
    int*  tileCount = (int*)ws;
    int*  typeBase  = (int*)(ws + 128);
    int*  blockHist = (int*)(ws + 512);
    int*  blockBase = (int*)(ws + 9216);
    int4* tiles     = (int4*)(ws + 17408);
    int*  idx       = (int*)(ws + 32768);
    unsigned short* Wb = (unsigned short*)(ws + 294912);

    hist_kernel<<<HB, 256, 0, stream>>>(types, W, Wb, blockHist);
    scan_kernel<<<1, 256, 0, stream>>>(blockHist, blockBase, typeBase, tiles, tileCount);
    scatter_kernel<<<HB, 256, 0, stream>>>(types, blockBase, typeBase, idx);
    gemm_kernel<<<dim3(MAXTILES, 1), 512, 0, stream>>>(x, b, Wb, tileCount, tiles, idx, out);
}